// Round 2
// baseline (681.370 us; speedup 1.0000x reference)
//
#include <hip/hip_runtime.h>

#define B_ 8
#define T_ 24
#define N_ 4096
#define FI 64
#define HH 128
#define CC 192
#define COLS 64
#define SX 72    // xT stride (bf16): 144B = 16B-aligned; 36 dw ≡ 4 mod 32 -> minimal-bank b128
#define SH 136   // hT stride (bf16): 272B = 16B-aligned; 68 dw ≡ 4 mod 32
#define SC2 136  // cT stride (bf16): same

typedef __bf16 bf16_t;
typedef bf16_t bf16x8 __attribute__((ext_vector_type(8)));
typedef bf16_t bf16x4 __attribute__((ext_vector_type(4)));
typedef float  f32x4  __attribute__((ext_vector_type(4)));

#define LOG2E 1.4426950408889634f

static __device__ __forceinline__ f32x4 mfma16(bf16x8 a, bf16x8 b, f32x4 c) {
    return __builtin_amdgcn_mfma_f32_16x16x32_bf16(a, b, c, 0, 0, 0);
}
static __device__ __forceinline__ float fast_rcp(float v) {
    return __builtin_amdgcn_rcpf(v);    // v_rcp_f32 (~1 ulp)
}
static __device__ __forceinline__ float fast_exp2(float v) {
    return __builtin_amdgcn_exp2f(v);   // v_exp_f32 (2^x)
}
// Barrier with LDS-only drain: __syncthreads() would emit s_waitcnt vmcnt(0)
// lgkmcnt(0), forcing every step to wait for output-store acks and x-prefetch
// loads. No barrier in this kernel needs vmem ordering (stores go to per-t
// disjoint addresses; prefetch values are register-carried with use-site waits).
#define BAR() asm volatile("s_waitcnt lgkmcnt(0)\n\ts_barrier" ::: "memory")

// Wave/row assignment (8 waves, 64 cols):
//   gates (256 rows): wave w owns M-tiles {w} (r rows) and {8+w} (z rows)
//   cand  (128 rows): wave w owns M-tile  {w}
//   => lane computing cand(ch,col) also holds r,z,h(ch,col) in registers.
//   out   (64 rows): wave w -> M-tile w>>1, N-tiles (w&1)*2+{0,1}
//
// Gate weights/bias pre-scaled by -log2e, cand by -2*log2e at load:
//   sigma(a) = rcp(1 + exp2(gtilde)),  gtilde = -log2e * a
//   tanh(v)  = 2*rcp(1 + exp2(ctilde)) - 1,  ctilde = -2*log2e * v
//
// 2-barrier schedule (x double-buffered):
//   [B_h] out(t-1) ; gates(t) ; sigmoid -> cT
//   [B_c] stage x_{t+1} -> xT[buf^1]; prefetch x_{t+2}; cand(t); tanh -> hT
__global__ __launch_bounds__(512, 4) void mgru_kernel(
    const float* __restrict__ x,
    const float* __restrict__ gate_w,
    const float* __restrict__ gate_b,
    const float* __restrict__ cand_w,
    const float* __restrict__ cand_b,
    const float* __restrict__ out_w,
    const float* __restrict__ out_b,
    float* __restrict__ out)
{
    __shared__ __align__(16) bf16_t xT[2][COLS * SX];  // [buf][col][ch 0..63]  x_t (bf16)
    __shared__ __align__(16) bf16_t hT[COLS * SH];     // [col][ch 0..127]      h   (bf16)
    __shared__ __align__(16) bf16_t cT[COLS * SC2];    // [col][ch 0..127]      r*h (bf16)

    const int tid  = threadIdx.x;
    const int wave = tid >> 6;          // 0..7
    const int lane = tid & 63;
    const int quad = lane >> 4;
    const int l16  = lane & 15;

    const int bb = blockIdx.x >> 6;           // batch
    const int n0 = (blockIdx.x & 63) * COLS;  // column tile base

    // h0 = 0
    for (int i = tid; i < COLS * HH; i += 512) {
        const int col = i >> 7, ch = i & (HH - 1);
        hT[col * SH + ch] = (bf16_t)0.0f;
    }

    // ---- weights -> register A-fragments (lane holds A[m0+l16][k0+quad*8+j]) ----
    bf16x8 gA[2][6];   // scaled by -log2e
    #pragma unroll
    for (int p = 0; p < 2; ++p) {
        const int m = p * 128 + wave * 16 + l16;
        #pragma unroll
        for (int kt = 0; kt < 6; ++kt) {
            bf16x8 f;
            #pragma unroll
            for (int j = 0; j < 8; ++j)
                f[j] = (bf16_t)(gate_w[(m * CC + kt * 32 + quad * 8 + j) * 2 + 1] * (-LOG2E));
            gA[p][kt] = f;
        }
    }
    bf16x8 cA[6];      // scaled by -2*log2e
    {
        const int m = wave * 16 + l16;
        #pragma unroll
        for (int kt = 0; kt < 6; ++kt) {
            bf16x8 f;
            #pragma unroll
            for (int j = 0; j < 8; ++j)
                f[j] = (bf16_t)(cand_w[(m * CC + kt * 32 + quad * 8 + j) * 2 + 1] * (-2.0f * LOG2E));
            cA[kt] = f;
        }
    }
    bf16x8 oA[4];
    {
        const int m = (wave >> 1) * 16 + l16;
        #pragma unroll
        for (int kt = 0; kt < 4; ++kt) {
            bf16x8 f;
            #pragma unroll
            for (int j = 0; j < 8; ++j)
                f[j] = (bf16_t)out_w[m * HH + kt * 32 + quad * 8 + j];
            oA[kt] = f;
        }
    }

    // ---- biases -> accumulator-init registers (same scales) ----
    f32x4 gBr, gBz, cB, oB;
    #pragma unroll
    for (int r = 0; r < 4; ++r) {
        gBr[r] = gate_b[wave * 16 + quad * 4 + r] * (-LOG2E);
        gBz[r] = gate_b[128 + wave * 16 + quad * 4 + r] * (-LOG2E);
        cB[r]  = cand_b[wave * 16 + quad * 4 + r] * (-2.0f * LOG2E);
        oB[r]  = out_b[(wave >> 1) * 16 + quad * 4 + r];
    }

    // fp32 master h, register-resident: hreg[nt][r] = h[wave*16+quad*4+r][nt*16+l16]
    f32x4 hreg[4];
    #pragma unroll
    for (int nt = 0; nt < 4; ++nt) hreg[nt] = f32x4{0.f, 0.f, 0.f, 0.f};

    const int xcol = tid >> 3;          // 0..63
    const int xcg  = (tid & 7) * 8;     // 8-float group of the 64 features
    const float* xbase = x   + ((size_t)bb * T_ * N_ + n0) * FI;
    float*       obase = out + ((size_t)bb * T_ * N_ + n0) * FI;

    // prologue: load + stage x_0, prefetch x_1
    f32x4 p0 = *(const f32x4*)(xbase + xcol * FI + xcg);
    f32x4 p1 = *(const f32x4*)(xbase + xcol * FI + xcg + 4);
    {
        bf16x8 xv;
        xv[0] = (bf16_t)p0[0]; xv[1] = (bf16_t)p0[1];
        xv[2] = (bf16_t)p0[2]; xv[3] = (bf16_t)p0[3];
        xv[4] = (bf16_t)p1[0]; xv[5] = (bf16_t)p1[1];
        xv[6] = (bf16_t)p1[2]; xv[7] = (bf16_t)p1[3];
        *(bf16x8*)&xT[0][xcol * SX + xcg] = xv;
    }
    {
        const float* xp = xbase + (size_t)1 * N_ * FI + xcol * FI + xcg;
        p0 = *(const f32x4*)xp;
        p1 = *(const f32x4*)(xp + 4);
    }
    BAR();                                             // x_0, h_0 ready

    int buf = 0;
    for (int t = 0; t < T_; ++t) {
        const bf16_t* __restrict__ xcur = xT[buf];

        // ---- gates = Wg~ @ [x_t; h_{t-1}]  (pre-scaled by -log2e) ----
        f32x4 ar[4], az[4];
        #pragma unroll
        for (int nt = 0; nt < 4; ++nt) { ar[nt] = gBr; az[nt] = gBz; }
        __builtin_amdgcn_s_setprio(1);
        #pragma unroll
        for (int kt = 0; kt < 6; ++kt) {
            const int ko = kt * 32 + quad * 8;
            bf16x8 b[4];
            #pragma unroll
            for (int nt = 0; nt < 4; ++nt)
                b[nt] = (kt < 2)
                    ? *(const bf16x8*)&xcur[(nt * 16 + l16) * SX + ko]
                    : *(const bf16x8*)&hT[(nt * 16 + l16) * SH + (ko - FI)];
            #pragma unroll
            for (int nt = 0; nt < 4; ++nt) {
                ar[nt] = mfma16(gA[0][kt], b[nt], ar[nt]);
                az[nt] = mfma16(gA[1][kt], b[nt], az[nt]);
            }
        }
        __builtin_amdgcn_s_setprio(0);

        // sigmoid: sigma = rcp(1 + exp2(gtilde)); r*h -> cT; z stays in registers
        f32x4 zreg[4];
        #pragma unroll
        for (int nt = 0; nt < 4; ++nt) {
            bf16x4 w;
            #pragma unroll
            for (int r = 0; r < 4; ++r) {
                const float rr = fast_rcp(1.0f + fast_exp2(ar[nt][r]));
                zreg[nt][r]    = fast_rcp(1.0f + fast_exp2(az[nt][r]));
                w[r] = (bf16_t)(rr * hreg[nt][r]);
            }
            *(bf16x4*)&cT[(nt * 16 + l16) * SC2 + wave * 16 + quad * 4] = w;
        }
        BAR();                                         // B_c: r*h ready

        // ---- stage x_{t+1} -> other buffer; prefetch x_{t+2} (overlaps cand) ----
        {
            bf16x8 xv;
            xv[0] = (bf16_t)p0[0]; xv[1] = (bf16_t)p0[1];
            xv[2] = (bf16_t)p0[2]; xv[3] = (bf16_t)p0[3];
            xv[4] = (bf16_t)p1[0]; xv[5] = (bf16_t)p1[1];
            xv[6] = (bf16_t)p1[2]; xv[7] = (bf16_t)p1[3];
            *(bf16x8*)&xT[buf ^ 1][xcol * SX + xcg] = xv;
        }
        {
            const int tn = (t + 2 < T_) ? t + 2 : T_ - 1;
            const float* xp = xbase + (size_t)tn * N_ * FI + xcol * FI + xcg;
            p0 = *(const f32x4*)xp;
            p1 = *(const f32x4*)(xp + 4);
        }

        // ---- cand = Wc~ @ [x_t; r*h]  (pre-scaled by -2*log2e) ----
        f32x4 cc[4];
        #pragma unroll
        for (int nt = 0; nt < 4; ++nt) cc[nt] = cB;
        __builtin_amdgcn_s_setprio(1);
        #pragma unroll
        for (int kt = 0; kt < 6; ++kt) {
            const int ko = kt * 32 + quad * 8;
            #pragma unroll
            for (int nt = 0; nt < 4; ++nt) {
                bf16x8 b = (kt < 2)
                    ? *(const bf16x8*)&xcur[(nt * 16 + l16) * SX + ko]
                    : *(const bf16x8*)&cT[(nt * 16 + l16) * SC2 + (ko - FI)];
                cc[nt] = mfma16(cA[kt], b, cc[nt]);
            }
        }
        __builtin_amdgcn_s_setprio(0);

        // tanh(v) = 2*rcp(1+exp2(ctilde)) - 1 ; state update; write bf16 h_t
        #pragma unroll
        for (int nt = 0; nt < 4; ++nt) {
            bf16x4 hw;
            #pragma unroll
            for (int r = 0; r < 4; ++r) {
                const float q  = fast_rcp(1.0f + fast_exp2(cc[nt][r]));
                const float ht = fmaf(2.0f, q, -1.0f);
                const float z  = zreg[nt][r];
                const float h  = hreg[nt][r];
                const float hn = fmaf(z, ht - h, h);   // (1-z)h + z*ht
                hreg[nt][r] = hn;
                hw[r] = (bf16_t)hn;
            }
            *(bf16x4*)&hT[(nt * 16 + l16) * SH + wave * 16 + quad * 4] = hw;
        }
        BAR();                                         // B_h: h_t (and x_{t+1}) ready

        // ---- o = relu(Wo @ h_t + b) -> direct global store ----
        {
            f32x4 oa[2];
            oa[0] = oB; oa[1] = oB;
            const int nb = (wave & 1) * 2;
            __builtin_amdgcn_s_setprio(1);
            #pragma unroll
            for (int kt = 0; kt < 4; ++kt) {
                const int ko = kt * 32 + quad * 8;
                bf16x8 b0 = *(const bf16x8*)&hT[(nb * 16 + l16) * SH + ko];
                bf16x8 b1 = *(const bf16x8*)&hT[((nb + 1) * 16 + l16) * SH + ko];
                oa[0] = mfma16(oA[kt], b0, oa[0]);
                oa[1] = mfma16(oA[kt], b1, oa[1]);
            }
            __builtin_amdgcn_s_setprio(0);
            #pragma unroll
            for (int j = 0; j < 2; ++j) {
                const int col = (nb + j) * 16 + l16;
                float* op = obase + (size_t)t * N_ * FI + col * FI + (wave >> 1) * 16 + quad * 4;
                f32x4 o;
                #pragma unroll
                for (int r = 0; r < 4; ++r) o[r] = fmaxf(oa[j][r], 0.0f);
                *(f32x4*)op = o;
            }
        }
        buf ^= 1;
    }
}

extern "C" void kernel_launch(void* const* d_in, const int* in_sizes, int n_in,
                              void* d_out, int out_size, void* d_ws, size_t ws_size,
                              hipStream_t stream) {
    (void)in_sizes; (void)n_in; (void)d_ws; (void)ws_size; (void)out_size;
    const float* x      = (const float*)d_in[0];
    const float* gate_w = (const float*)d_in[1];
    const float* gate_b = (const float*)d_in[2];
    const float* cand_w = (const float*)d_in[3];
    const float* cand_b = (const float*)d_in[4];
    const float* out_w  = (const float*)d_in[5];
    const float* out_b  = (const float*)d_in[6];
    float* out = (float*)d_out;
    mgru_kernel<<<dim3(B_ * (N_ / COLS)), dim3(512), 0, stream>>>(
        x, gate_w, gate_b, cand_w, cand_b, out_w, out_b, out);
}

// Round 3
// 455.391 us; speedup vs baseline: 1.4962x; 1.4962x over previous
//
#include <hip/hip_runtime.h>

#define B_ 8
#define T_ 24
#define N_ 4096
#define FI 64
#define HH 128
#define CC 192
#define COLS 64
#define SX 72    // xT stride (bf16): 144B = 16B-aligned; 36 dw ≡ 4 mod 32 -> minimal-bank b128
#define SH 136   // hT stride (bf16): 272B = 16B-aligned; 68 dw ≡ 4 mod 32
#define SC2 136  // cT stride (bf16): same

typedef __bf16 bf16_t;
typedef bf16_t bf16x8 __attribute__((ext_vector_type(8)));
typedef bf16_t bf16x4 __attribute__((ext_vector_type(4)));
typedef float  f32x4  __attribute__((ext_vector_type(4)));

#define LOG2E 1.4426950408889634f

static __device__ __forceinline__ f32x4 mfma16(bf16x8 a, bf16x8 b, f32x4 c) {
    return __builtin_amdgcn_mfma_f32_16x16x32_bf16(a, b, c, 0, 0, 0);
}
static __device__ __forceinline__ float fast_rcp(float v) {
    return __builtin_amdgcn_rcpf(v);    // v_rcp_f32 (~1 ulp)
}
static __device__ __forceinline__ float fast_exp2(float v) {
    return __builtin_amdgcn_exp2f(v);   // v_exp_f32 (2^x)
}
// Barrier with LDS-only drain: __syncthreads() would emit s_waitcnt vmcnt(0)
// lgkmcnt(0), forcing every step to wait for output-store acks and x-prefetch
// loads. No barrier in this kernel needs vmem ordering (stores go to per-t
// disjoint addresses; prefetch values are register-carried with use-site waits).
#define BAR() asm volatile("s_waitcnt lgkmcnt(0)\n\ts_barrier" ::: "memory")

// Wave/row assignment (8 waves, 64 cols):
//   gates (256 rows): wave w owns M-tiles {w} (r rows) and {8+w} (z rows)
//   cand  (128 rows): wave w owns M-tile  {w}
//   => lane computing cand(ch,col) also holds r,z,h(ch,col) in registers.
//   out   (64 rows): wave w -> M-tile w>>1, N-tiles (w&1)*2+{0,1}
//
// Gate weights/bias pre-scaled by -log2e, cand by -2*log2e at load:
//   sigma(a) = rcp(1 + exp2(gtilde)),  gtilde = -log2e * a
//   tanh(v)  = 2*rcp(1 + exp2(ctilde)) - 1,  ctilde = -2*log2e * v
//
// __launch_bounds__(512, 2): EXACTLY 2 waves/EU (= 2 blocks/CU with 8-wave
// blocks). (512,4) capped the allocator and spilled the weight fragments:
// FETCH_SIZE went 103 MB -> 1.13 GB of scratch traffic. Do not raise.
//
// 2-barrier schedule (x double-buffered):
//   [B_h] out(t-1) ; gates(t) ; sigmoid -> cT
//   [B_c] stage x_{t+1} -> xT[buf^1]; prefetch x_{t+2}; cand(t); tanh -> hT
__global__ __launch_bounds__(512, 2) void mgru_kernel(
    const float* __restrict__ x,
    const float* __restrict__ gate_w,
    const float* __restrict__ gate_b,
    const float* __restrict__ cand_w,
    const float* __restrict__ cand_b,
    const float* __restrict__ out_w,
    const float* __restrict__ out_b,
    float* __restrict__ out)
{
    __shared__ __align__(16) bf16_t xT[2][COLS * SX];  // [buf][col][ch 0..63]  x_t (bf16)
    __shared__ __align__(16) bf16_t hT[COLS * SH];     // [col][ch 0..127]      h   (bf16)
    __shared__ __align__(16) bf16_t cT[COLS * SC2];    // [col][ch 0..127]      r*h (bf16)

    const int tid  = threadIdx.x;
    const int wave = tid >> 6;          // 0..7
    const int lane = tid & 63;
    const int quad = lane >> 4;
    const int l16  = lane & 15;

    const int bb = blockIdx.x >> 6;           // batch
    const int n0 = (blockIdx.x & 63) * COLS;  // column tile base

    // h0 = 0
    for (int i = tid; i < COLS * HH; i += 512) {
        const int col = i >> 7, ch = i & (HH - 1);
        hT[col * SH + ch] = (bf16_t)0.0f;
    }

    // ---- weights -> register A-fragments (lane holds A[m0+l16][k0+quad*8+j]) ----
    bf16x8 gA[2][6];   // scaled by -log2e
    #pragma unroll
    for (int p = 0; p < 2; ++p) {
        const int m = p * 128 + wave * 16 + l16;
        #pragma unroll
        for (int kt = 0; kt < 6; ++kt) {
            bf16x8 f;
            #pragma unroll
            for (int j = 0; j < 8; ++j)
                f[j] = (bf16_t)(gate_w[(m * CC + kt * 32 + quad * 8 + j) * 2 + 1] * (-LOG2E));
            gA[p][kt] = f;
        }
    }
    bf16x8 cA[6];      // scaled by -2*log2e
    {
        const int m = wave * 16 + l16;
        #pragma unroll
        for (int kt = 0; kt < 6; ++kt) {
            bf16x8 f;
            #pragma unroll
            for (int j = 0; j < 8; ++j)
                f[j] = (bf16_t)(cand_w[(m * CC + kt * 32 + quad * 8 + j) * 2 + 1] * (-2.0f * LOG2E));
            cA[kt] = f;
        }
    }
    bf16x8 oA[4];
    {
        const int m = (wave >> 1) * 16 + l16;
        #pragma unroll
        for (int kt = 0; kt < 4; ++kt) {
            bf16x8 f;
            #pragma unroll
            for (int j = 0; j < 8; ++j)
                f[j] = (bf16_t)out_w[m * HH + kt * 32 + quad * 8 + j];
            oA[kt] = f;
        }
    }

    // ---- biases -> accumulator-init registers (same scales) ----
    f32x4 gBr, gBz, cB, oB;
    #pragma unroll
    for (int r = 0; r < 4; ++r) {
        gBr[r] = gate_b[wave * 16 + quad * 4 + r] * (-LOG2E);
        gBz[r] = gate_b[128 + wave * 16 + quad * 4 + r] * (-LOG2E);
        cB[r]  = cand_b[wave * 16 + quad * 4 + r] * (-2.0f * LOG2E);
        oB[r]  = out_b[(wave >> 1) * 16 + quad * 4 + r];
    }

    // fp32 master h, register-resident: hreg[nt][r] = h[wave*16+quad*4+r][nt*16+l16]
    f32x4 hreg[4];
    #pragma unroll
    for (int nt = 0; nt < 4; ++nt) hreg[nt] = f32x4{0.f, 0.f, 0.f, 0.f};

    const int xcol = tid >> 3;          // 0..63
    const int xcg  = (tid & 7) * 8;     // 8-float group of the 64 features
    const float* xbase = x   + ((size_t)bb * T_ * N_ + n0) * FI;
    float*       obase = out + ((size_t)bb * T_ * N_ + n0) * FI;

    // prologue: load + stage x_0, prefetch x_1
    f32x4 p0 = *(const f32x4*)(xbase + xcol * FI + xcg);
    f32x4 p1 = *(const f32x4*)(xbase + xcol * FI + xcg + 4);
    {
        bf16x8 xv;
        xv[0] = (bf16_t)p0[0]; xv[1] = (bf16_t)p0[1];
        xv[2] = (bf16_t)p0[2]; xv[3] = (bf16_t)p0[3];
        xv[4] = (bf16_t)p1[0]; xv[5] = (bf16_t)p1[1];
        xv[6] = (bf16_t)p1[2]; xv[7] = (bf16_t)p1[3];
        *(bf16x8*)&xT[0][xcol * SX + xcg] = xv;
    }
    {
        const float* xp = xbase + (size_t)1 * N_ * FI + xcol * FI + xcg;
        p0 = *(const f32x4*)xp;
        p1 = *(const f32x4*)(xp + 4);
    }
    BAR();                                             // x_0, h_0 ready

    int buf = 0;
    for (int t = 0; t < T_; ++t) {
        const bf16_t* __restrict__ xcur = xT[buf];

        // ---- gates = Wg~ @ [x_t; h_{t-1}]  (pre-scaled by -log2e) ----
        f32x4 ar[4], az[4];
        #pragma unroll
        for (int nt = 0; nt < 4; ++nt) { ar[nt] = gBr; az[nt] = gBz; }
        __builtin_amdgcn_s_setprio(1);
        #pragma unroll
        for (int kt = 0; kt < 6; ++kt) {
            const int ko = kt * 32 + quad * 8;
            bf16x8 b[4];
            #pragma unroll
            for (int nt = 0; nt < 4; ++nt)
                b[nt] = (kt < 2)
                    ? *(const bf16x8*)&xcur[(nt * 16 + l16) * SX + ko]
                    : *(const bf16x8*)&hT[(nt * 16 + l16) * SH + (ko - FI)];
            #pragma unroll
            for (int nt = 0; nt < 4; ++nt) {
                ar[nt] = mfma16(gA[0][kt], b[nt], ar[nt]);
                az[nt] = mfma16(gA[1][kt], b[nt], az[nt]);
            }
        }
        __builtin_amdgcn_s_setprio(0);

        // sigmoid: sigma = rcp(1 + exp2(gtilde)); r*h -> cT; z stays in registers
        f32x4 zreg[4];
        #pragma unroll
        for (int nt = 0; nt < 4; ++nt) {
            bf16x4 w;
            #pragma unroll
            for (int r = 0; r < 4; ++r) {
                const float rr = fast_rcp(1.0f + fast_exp2(ar[nt][r]));
                zreg[nt][r]    = fast_rcp(1.0f + fast_exp2(az[nt][r]));
                w[r] = (bf16_t)(rr * hreg[nt][r]);
            }
            *(bf16x4*)&cT[(nt * 16 + l16) * SC2 + wave * 16 + quad * 4] = w;
        }
        BAR();                                         // B_c: r*h ready

        // ---- stage x_{t+1} -> other buffer; prefetch x_{t+2} (overlaps cand) ----
        {
            bf16x8 xv;
            xv[0] = (bf16_t)p0[0]; xv[1] = (bf16_t)p0[1];
            xv[2] = (bf16_t)p0[2]; xv[3] = (bf16_t)p0[3];
            xv[4] = (bf16_t)p1[0]; xv[5] = (bf16_t)p1[1];
            xv[6] = (bf16_t)p1[2]; xv[7] = (bf16_t)p1[3];
            *(bf16x8*)&xT[buf ^ 1][xcol * SX + xcg] = xv;
        }
        {
            const int tn = (t + 2 < T_) ? t + 2 : T_ - 1;
            const float* xp = xbase + (size_t)tn * N_ * FI + xcol * FI + xcg;
            p0 = *(const f32x4*)xp;
            p1 = *(const f32x4*)(xp + 4);
        }

        // ---- cand = Wc~ @ [x_t; r*h]  (pre-scaled by -2*log2e) ----
        f32x4 cc[4];
        #pragma unroll
        for (int nt = 0; nt < 4; ++nt) cc[nt] = cB;
        __builtin_amdgcn_s_setprio(1);
        #pragma unroll
        for (int kt = 0; kt < 6; ++kt) {
            const int ko = kt * 32 + quad * 8;
            #pragma unroll
            for (int nt = 0; nt < 4; ++nt) {
                bf16x8 b = (kt < 2)
                    ? *(const bf16x8*)&xcur[(nt * 16 + l16) * SX + ko]
                    : *(const bf16x8*)&cT[(nt * 16 + l16) * SC2 + (ko - FI)];
                cc[nt] = mfma16(cA[kt], b, cc[nt]);
            }
        }
        __builtin_amdgcn_s_setprio(0);

        // tanh(v) = 2*rcp(1+exp2(ctilde)) - 1 ; state update; write bf16 h_t
        #pragma unroll
        for (int nt = 0; nt < 4; ++nt) {
            bf16x4 hw;
            #pragma unroll
            for (int r = 0; r < 4; ++r) {
                const float q  = fast_rcp(1.0f + fast_exp2(cc[nt][r]));
                const float ht = fmaf(2.0f, q, -1.0f);
                const float z  = zreg[nt][r];
                const float h  = hreg[nt][r];
                const float hn = fmaf(z, ht - h, h);   // (1-z)h + z*ht
                hreg[nt][r] = hn;
                hw[r] = (bf16_t)hn;
            }
            *(bf16x4*)&hT[(nt * 16 + l16) * SH + wave * 16 + quad * 4] = hw;
        }
        BAR();                                         // B_h: h_t (and x_{t+1}) ready

        // ---- o = relu(Wo @ h_t + b) -> direct global store ----
        {
            f32x4 oa[2];
            oa[0] = oB; oa[1] = oB;
            const int nb = (wave & 1) * 2;
            __builtin_amdgcn_s_setprio(1);
            #pragma unroll
            for (int kt = 0; kt < 4; ++kt) {
                const int ko = kt * 32 + quad * 8;
                bf16x8 b0 = *(const bf16x8*)&hT[(nb * 16 + l16) * SH + ko];
                bf16x8 b1 = *(const bf16x8*)&hT[((nb + 1) * 16 + l16) * SH + ko];
                oa[0] = mfma16(oA[kt], b0, oa[0]);
                oa[1] = mfma16(oA[kt], b1, oa[1]);
            }
            __builtin_amdgcn_s_setprio(0);
            #pragma unroll
            for (int j = 0; j < 2; ++j) {
                const int col = (nb + j) * 16 + l16;
                float* op = obase + (size_t)t * N_ * FI + col * FI + (wave >> 1) * 16 + quad * 4;
                f32x4 o;
                #pragma unroll
                for (int r = 0; r < 4; ++r) o[r] = fmaxf(oa[j][r], 0.0f);
                *(f32x4*)op = o;
            }
        }
        buf ^= 1;
    }
}

extern "C" void kernel_launch(void* const* d_in, const int* in_sizes, int n_in,
                              void* d_out, int out_size, void* d_ws, size_t ws_size,
                              hipStream_t stream) {
    (void)in_sizes; (void)n_in; (void)d_ws; (void)ws_size; (void)out_size;
    const float* x      = (const float*)d_in[0];
    const float* gate_w = (const float*)d_in[1];
    const float* gate_b = (const float*)d_in[2];
    const float* cand_w = (const float*)d_in[3];
    const float* cand_b = (const float*)d_in[4];
    const float* out_b_ = (const float*)d_in[6];
    const float* out_w  = (const float*)d_in[5];
    float* out = (float*)d_out;
    mgru_kernel<<<dim3(B_ * (N_ / COLS)), dim3(512), 0, stream>>>(
        x, gate_w, gate_b, cand_w, cand_b, out_w, out_b_, out);
}